// Round 7
// baseline (1691.648 us; speedup 1.0000x reference)
//
#include <hip/hip_runtime.h>
#include <stdint.h>

// CA model constants (match reference)
#define BB 8
#define CC 16
#define HH_ 128
#define WW 128
#define HIDN 128
#define HWSZ (HH_ * WW)          // 16384
#define NPIX (BB * HWSZ)         // 131072
#define NSTEPS 16

// ---------------------------------------------------------------------------
// Threefry-2x32, 20 rounds — exact JAX implementation (partitionable mode).
// ---------------------------------------------------------------------------
__host__ __device__ inline void threefry2x32(uint32_t k0, uint32_t k1,
                                             uint32_t x0, uint32_t x1,
                                             uint32_t* o0, uint32_t* o1) {
  uint32_t ks[3] = {k0, k1, k0 ^ k1 ^ 0x1BD11BDAu};
  const uint32_t rots[2][4] = {{13u, 15u, 26u, 6u}, {17u, 29u, 16u, 24u}};
  x0 += ks[0];
  x1 += ks[1];
#pragma unroll
  for (int g = 0; g < 5; ++g) {
    const uint32_t* r = rots[g & 1];
#pragma unroll
    for (int i = 0; i < 4; ++i) {
      x0 += x1;
      x1 = (x1 << r[i]) | (x1 >> (32u - r[i]));
      x1 ^= x0;
    }
    x0 += ks[(g + 1) % 3];
    x1 += ks[(g + 2) % 3] + (uint32_t)(g + 1);
  }
  *o0 = x0;
  *o1 = x1;
}

__device__ __forceinline__ float jax_mask_bit(uint32_t key0, uint32_t key1, int g) {
  uint32_t t0, t1;
  threefry2x32(key0, key1, 0u, (uint32_t)g, &t0, &t1);
  uint32_t bits = t0 ^ t1;
  float u = __uint_as_float((bits >> 9) | 0x3f800000u) - 1.0f;
  return (u < 0.5f) ? 1.0f : 0.0f;
}

// One hidden unit: layer-1 dot(48) + relu + layer-2 rank-1 update.
// b1 seeded into a0 (bit-identical FMA order to the 58-us R0 baseline).
// w2 read as uniform scalar loads (sL1-resident 8 KB, ~30 cy hits, hidden
// behind the 48 layer-1 FMAs). All buf/p/diff indices compile-time.
__device__ __forceinline__ void mlp_row(int hh, const float4 (&buf)[12],
                                        const float (&p)[48],
                                        float (&diff)[16],
                                        const float* __restrict__ b1,
                                        const float* __restrict__ w2) {
  float a0 = b1[hh], a1 = 0.f, a2 = 0.f, a3 = 0.f;
#pragma unroll
  for (int q = 0; q < 3; ++q) {
    float4 w0 = buf[q * 4 + 0];
    float4 w1v = buf[q * 4 + 1];
    float4 w2v = buf[q * 4 + 2];
    float4 w3 = buf[q * 4 + 3];
    const int base = q * 16;
    a0 = fmaf(w0.x, p[base + 0], a0);
    a0 = fmaf(w0.y, p[base + 1], a0);
    a0 = fmaf(w0.z, p[base + 2], a0);
    a0 = fmaf(w0.w, p[base + 3], a0);
    a1 = fmaf(w1v.x, p[base + 4], a1);
    a1 = fmaf(w1v.y, p[base + 5], a1);
    a1 = fmaf(w1v.z, p[base + 6], a1);
    a1 = fmaf(w1v.w, p[base + 7], a1);
    a2 = fmaf(w2v.x, p[base + 8], a2);
    a2 = fmaf(w2v.y, p[base + 9], a2);
    a2 = fmaf(w2v.z, p[base + 10], a2);
    a2 = fmaf(w2v.w, p[base + 11], a2);
    a3 = fmaf(w3.x, p[base + 12], a3);
    a3 = fmaf(w3.y, p[base + 13], a3);
    a3 = fmaf(w3.z, p[base + 14], a3);
    a3 = fmaf(w3.w, p[base + 15], a3);
  }
  float acch = fmaxf((a0 + a1) + (a2 + a3), 0.f);
#pragma unroll
  for (int o = 0; o < CC; ++o)
    diff[o] = fmaf(w2[o * HIDN + hh], acch, diff[o]);  // uniform s_load_dword
}

// ---------------------------------------------------------------------------
// Kernel A: sobel perception + MLP + mask -> writes "new" state to nxt
//
// R7: w1 via VMEM broadcast with MANUAL double-buffer; w2 via scalar column
// loads; NO LDS. Path ledger (all measured):
//   s_load w1 (R0, 58us): out-of-order scalar returns force full lgkmcnt(0)
//     drain/iter; 48-SGPR row at the 102 ceiling -> cannot double-buffer.
//     R6 proved more waves DON'T hide it (sL1-miss serialization, shared
//     per-CU): occupancy 2x -> dur 72us, VALUBusy flat at 26%.
//   LDS broadcast (R1, 80us): DS pipe bound, 16 b128 x 8 waves x 12cy.
//   VMEM naive (R3, 130us): compiler reused dest VGPRs -> vmcnt(0)/iter.
// This kernel: two named float4[12] buffers, prefetch row hh+2 while
// computing row hh. VMEM returns in order; use-to-wait distance ~150-190cy
// covers the ~200cy vL1 hit; w1 (24KB) is vL1-resident (32KB) since all 8
// waves walk the same 128 rows. w2 moves off the DS pipe onto the now-idle
// scalar pipe (8KB, sL1-resident). Expected window: VALU-bound, 272cy/SIMD.
// ---------------------------------------------------------------------------
__global__ __launch_bounds__(256, 2) void ca_step_mlp(
    const float* __restrict__ cur, const float* __restrict__ w1,
    const float* __restrict__ b1, const float* __restrict__ w2,
    const float* __restrict__ b2, float* __restrict__ nxt,
    uint32_t key0, uint32_t key1) {
  const int g = blockIdx.x * 256 + threadIdx.x;  // 0..NPIX-1
  const int b = g >> 14;
  const int hw = g & (HWSZ - 1);
  const int h = hw >> 7;
  const int w = hw & (WW - 1);

  const bool hu = h > 0, hd = h < HH_ - 1, wl = w > 0, wr = w < WW - 1;
  const int du = hu ? -WW : 0;
  const int dd = hd ? WW : 0;
  const int dl = wl ? -1 : 0;
  const int dr = wr ? 1 : 0;

  const float* xb = cur + (size_t)b * CC * HWSZ + hw;

  // perception: [ident(16) | sobel_x(16) | sobel_y(16)]
  float p[48];
#pragma unroll
  for (int c = 0; c < CC; ++c) {
    const float* xc = xb + c * HWSZ;
    float n00 = xc[du + dl]; if (!(hu && wl)) n00 = 0.f;
    float n01 = xc[du];      if (!hu)         n01 = 0.f;
    float n02 = xc[du + dr]; if (!(hu && wr)) n02 = 0.f;
    float n10 = xc[dl];      if (!wl)         n10 = 0.f;
    float n11 = xc[0];
    float n12 = xc[dr];      if (!wr)         n12 = 0.f;
    float n20 = xc[dd + dl]; if (!(hd && wl)) n20 = 0.f;
    float n21 = xc[dd];      if (!hd)         n21 = 0.f;
    float n22 = xc[dd + dr]; if (!(hd && wr)) n22 = 0.f;
    p[c] = n11;
    p[16 + c] = (n00 - n02 + 2.f * (n10 - n12) + n20 - n22) * 0.125f;
    p[32 + c] = (n00 + 2.f * n01 + n02 - n20 - 2.f * n21 - n22) * 0.125f;
  }

  float diff[16];
#pragma unroll
  for (int o = 0; o < CC; ++o) diff[o] = b2[o];  // uniform -> s_load

  // Opaque VGPR zero: marks the w1 base divergent so loads stay on the VMEM
  // path (global_load_dwordx4) and cannot be promoted to s_load (R3 proved
  // the trick holds: SGPR 112 -> 48).
  int vzero;
  asm volatile("v_mov_b32 %0, 0" : "=v"(vzero));
  const float4* w1r = (const float4*)w1 + vzero;

  // Manual double-buffer: preload rows 0 and 1.
  float4 bufA[12], bufB[12];
#pragma unroll
  for (int j = 0; j < 12; ++j) bufA[j] = w1r[j];
#pragma unroll
  for (int j = 0; j < 12; ++j) bufB[j] = w1r[12 + j];

#pragma unroll 1
  for (int hh = 0; hh < HIDN; hh += 2) {
    mlp_row(hh, bufA, p, diff, b1, w2);
#pragma unroll
    for (int j = 0; j < 12; ++j)
      bufA[j] = w1r[((hh + 2) & (HIDN - 1)) * 12 + j];  // prefetch row hh+2
    mlp_row(hh + 1, bufB, p, diff, b1, w2);
#pragma unroll
    for (int j = 0; j < 12; ++j)
      bufB[j] = w1r[((hh + 3) & (HIDN - 1)) * 12 + j];  // prefetch row hh+3
  }

  const float m = jax_mask_bit(key0, key1, g);

  float* nb = nxt + (size_t)b * CC * HWSZ + hw;
#pragma unroll
  for (int c = 0; c < CC; ++c) {
    nb[c * HWSZ] = fmaf(diff[c], m, p[c]);  // exact: m in {0,1}
  }
}

// ---------------------------------------------------------------------------
// Kernel B: 3x3 max-pool on alpha (ch 3), alive gate, write next state
// ---------------------------------------------------------------------------
__global__ __launch_bounds__(256) void ca_step_alive(
    const float* __restrict__ nw, float* __restrict__ out) {
  const int g = blockIdx.x * 256 + threadIdx.x;
  const int b = g >> 14;
  const int hw = g & (HWSZ - 1);
  const int h = hw >> 7;
  const int w = hw & (WW - 1);
  const bool hu = h > 0, hd = h < HH_ - 1, wl = w > 0, wr = w < WW - 1;

  const float* ab = nw + ((size_t)b * CC + 3) * HWSZ + hw;
  float pooled = ab[0];
  if (hu) {
    pooled = fmaxf(pooled, ab[-WW]);
    if (wl) pooled = fmaxf(pooled, ab[-WW - 1]);
    if (wr) pooled = fmaxf(pooled, ab[-WW + 1]);
  }
  if (hd) {
    pooled = fmaxf(pooled, ab[WW]);
    if (wl) pooled = fmaxf(pooled, ab[WW - 1]);
    if (wr) pooled = fmaxf(pooled, ab[WW + 1]);
  }
  if (wl) pooled = fmaxf(pooled, ab[-1]);
  if (wr) pooled = fmaxf(pooled, ab[1]);

  const float alive = (pooled > 0.1f) ? 1.0f : 0.0f;

  const float* nb = nw + (size_t)b * CC * HWSZ + hw;
  float* ob = out + (size_t)b * CC * HWSZ + hw;
#pragma unroll
  for (int c = 0; c < CC; ++c) ob[c * HWSZ] = nb[c * HWSZ] * alive;
}

// ---------------------------------------------------------------------------
extern "C" void kernel_launch(void* const* d_in, const int* in_sizes, int n_in,
                              void* d_out, int out_size, void* d_ws,
                              size_t ws_size, hipStream_t stream) {
  const float* x = (const float*)d_in[0];
  const float* w1 = (const float*)d_in[1];
  const float* b1 = (const float*)d_in[2];
  const float* w2 = (const float*)d_in[3];
  const float* b2 = (const float*)d_in[4];
  // d_in[5] = n_steps (16) — fixed at compile time

  float* out = (float*)d_out;
  float* nbuf = (float*)d_ws;  // NPIX*CC*4 = 8 MB scratch

  // step keys from split(key(42), 16), partitionable threefry
  uint32_t k0s[NSTEPS], k1s[NSTEPS];
  for (int s = 0; s < NSTEPS; ++s)
    threefry2x32(0u, 42u, 0u, (uint32_t)s, &k0s[s], &k1s[s]);

  dim3 grid(NPIX / 256), block(256);
  for (int s = 0; s < NSTEPS; ++s) {
    const float* src = (s == 0) ? x : out;
    ca_step_mlp<<<grid, block, 0, stream>>>(src, w1, b1, w2, b2, nbuf,
                                            k0s[s], k1s[s]);
    ca_step_alive<<<grid, block, 0, stream>>>(nbuf, out);
  }
}

// Round 8
// 1673.089 us; speedup vs baseline: 1.0111x; 1.0111x over previous
//
#include <hip/hip_runtime.h>
#include <stdint.h>

// CA model constants (match reference)
#define BB 8
#define CC 16
#define HH_ 128
#define WW 128
#define HIDN 128
#define HWSZ (HH_ * WW)          // 16384
#define NPIX (BB * HWSZ)         // 131072
#define NSTEPS 16

// ---------------------------------------------------------------------------
// Threefry-2x32, 20 rounds — exact JAX implementation (partitionable mode).
// ---------------------------------------------------------------------------
__host__ __device__ inline void threefry2x32(uint32_t k0, uint32_t k1,
                                             uint32_t x0, uint32_t x1,
                                             uint32_t* o0, uint32_t* o1) {
  uint32_t ks[3] = {k0, k1, k0 ^ k1 ^ 0x1BD11BDAu};
  const uint32_t rots[2][4] = {{13u, 15u, 26u, 6u}, {17u, 29u, 16u, 24u}};
  x0 += ks[0];
  x1 += ks[1];
#pragma unroll
  for (int g = 0; g < 5; ++g) {
    const uint32_t* r = rots[g & 1];
#pragma unroll
    for (int i = 0; i < 4; ++i) {
      x0 += x1;
      x1 = (x1 << r[i]) | (x1 >> (32u - r[i]));
      x1 ^= x0;
    }
    x0 += ks[(g + 1) % 3];
    x1 += ks[(g + 2) % 3] + (uint32_t)(g + 1);
  }
  *o0 = x0;
  *o1 = x1;
}

__device__ __forceinline__ float jax_mask_bit(uint32_t key0, uint32_t key1, int g) {
  uint32_t t0, t1;
  threefry2x32(key0, key1, 0u, (uint32_t)g, &t0, &t1);
  uint32_t bits = t0 ^ t1;
  float u = __uint_as_float((bits >> 9) | 0x3f800000u) - 1.0f;
  return (u < 0.5f) ? 1.0f : 0.0f;
}

// One hidden unit: layer-1 dot(48) + relu + layer-2 rank-1 update.
// b1 seeded into a0 (same FMA order as the R0/R7 kernels, absmax-verified).
// w2 via uniform scalar loads (8 KB, sL1-resident now that w1 is off the
// scalar pipe — R7 confirmed: SGPR_Count 112, w2 drains fast).
__device__ __forceinline__ void mlp_row(int hh, const float4 (&buf)[12],
                                        const float (&p)[48],
                                        float (&diff)[16],
                                        const float* __restrict__ b1,
                                        const float* __restrict__ w2) {
  float a0 = b1[hh], a1 = 0.f, a2 = 0.f, a3 = 0.f;
#pragma unroll
  for (int q = 0; q < 3; ++q) {
    float4 w0 = buf[q * 4 + 0];
    float4 w1v = buf[q * 4 + 1];
    float4 w2v = buf[q * 4 + 2];
    float4 w3 = buf[q * 4 + 3];
    const int base = q * 16;
    a0 = fmaf(w0.x, p[base + 0], a0);
    a0 = fmaf(w0.y, p[base + 1], a0);
    a0 = fmaf(w0.z, p[base + 2], a0);
    a0 = fmaf(w0.w, p[base + 3], a0);
    a1 = fmaf(w1v.x, p[base + 4], a1);
    a1 = fmaf(w1v.y, p[base + 5], a1);
    a1 = fmaf(w1v.z, p[base + 6], a1);
    a1 = fmaf(w1v.w, p[base + 7], a1);
    a2 = fmaf(w2v.x, p[base + 8], a2);
    a2 = fmaf(w2v.y, p[base + 9], a2);
    a2 = fmaf(w2v.z, p[base + 10], a2);
    a2 = fmaf(w2v.w, p[base + 11], a2);
    a3 = fmaf(w3.x, p[base + 12], a3);
    a3 = fmaf(w3.y, p[base + 13], a3);
    a3 = fmaf(w3.z, p[base + 14], a3);
    a3 = fmaf(w3.w, p[base + 15], a3);
  }
  float acch = fmaxf((a0 + a1) + (a2 + a3), 0.f);
#pragma unroll
  for (int o = 0; o < CC; ++o)
    diff[o] = fmaf(w2[o * HIDN + hh], acch, diff[o]);  // uniform s_load_dword
}

// ---------------------------------------------------------------------------
// Kernel A: sobel perception + MLP + mask -> writes "new" state to nxt
//
// R8 = R7 + sched_barrier(0) pinning of the prefetch blocks (rule #18:
// hipcc sinks/reorders around source-level pipelining unless fenced).
// R7's tripwire fired: VGPR=92 => the compiler sank the 12-load prefetch
// into the use site, collapsing the double-buffer -> full vmcnt drain per
// row (108us, VALUBusy 32%). The VMEM path is architecturally right (many
// outstanding loads, counted in-order vmcnt waits; R6 proved the scalar
// pipe's misses serialize per-CU and occupancy can't hide them) — it
// failed on SCHEDULING. sched_barrier(0) after each prefetch block forbids
// sinking; the WAR dep on buf stops illegal hoisting. Steady state: 24
// loads in flight, use waits vmcnt(12) after a full mlp_row (~300 cy VALU)
// which covers the ~200cy vL1/L2 hit. Expect VALU-bound, ~18-25us.
// ---------------------------------------------------------------------------
__global__ __launch_bounds__(256, 2) void ca_step_mlp(
    const float* __restrict__ cur, const float* __restrict__ w1,
    const float* __restrict__ b1, const float* __restrict__ w2,
    const float* __restrict__ b2, float* __restrict__ nxt,
    uint32_t key0, uint32_t key1) {
  const int g = blockIdx.x * 256 + threadIdx.x;  // 0..NPIX-1
  const int b = g >> 14;
  const int hw = g & (HWSZ - 1);
  const int h = hw >> 7;
  const int w = hw & (WW - 1);

  const bool hu = h > 0, hd = h < HH_ - 1, wl = w > 0, wr = w < WW - 1;
  const int du = hu ? -WW : 0;
  const int dd = hd ? WW : 0;
  const int dl = wl ? -1 : 0;
  const int dr = wr ? 1 : 0;

  const float* xb = cur + (size_t)b * CC * HWSZ + hw;

  // perception: [ident(16) | sobel_x(16) | sobel_y(16)]
  float p[48];
#pragma unroll
  for (int c = 0; c < CC; ++c) {
    const float* xc = xb + c * HWSZ;
    float n00 = xc[du + dl]; if (!(hu && wl)) n00 = 0.f;
    float n01 = xc[du];      if (!hu)         n01 = 0.f;
    float n02 = xc[du + dr]; if (!(hu && wr)) n02 = 0.f;
    float n10 = xc[dl];      if (!wl)         n10 = 0.f;
    float n11 = xc[0];
    float n12 = xc[dr];      if (!wr)         n12 = 0.f;
    float n20 = xc[dd + dl]; if (!(hd && wl)) n20 = 0.f;
    float n21 = xc[dd];      if (!hd)         n21 = 0.f;
    float n22 = xc[dd + dr]; if (!(hd && wr)) n22 = 0.f;
    p[c] = n11;
    p[16 + c] = (n00 - n02 + 2.f * (n10 - n12) + n20 - n22) * 0.125f;
    p[32 + c] = (n00 + 2.f * n01 + n02 - n20 - 2.f * n21 - n22) * 0.125f;
  }

  float diff[16];
#pragma unroll
  for (int o = 0; o < CC; ++o) diff[o] = b2[o];  // uniform -> s_load

  // Opaque VGPR zero: keeps w1 loads on the VMEM path (cannot be promoted
  // to s_load — R3/R7 confirmed via SGPR counts).
  int vzero;
  asm volatile("v_mov_b32 %0, 0" : "=v"(vzero));
  const float4* w1r = (const float4*)w1 + vzero;

  // Manual double-buffer: preload rows 0 and 1, pinned by sched_barrier.
  float4 bufA[12], bufB[12];
#pragma unroll
  for (int j = 0; j < 12; ++j) bufA[j] = w1r[j];
#pragma unroll
  for (int j = 0; j < 12; ++j) bufB[j] = w1r[12 + j];
  __builtin_amdgcn_sched_barrier(0);

#pragma unroll 1
  for (int hh = 0; hh < HIDN; hh += 2) {
    mlp_row(hh, bufA, p, diff, b1, w2);
#pragma unroll
    for (int j = 0; j < 12; ++j)
      bufA[j] = w1r[((hh + 2) & (HIDN - 1)) * 12 + j];  // prefetch row hh+2
    __builtin_amdgcn_sched_barrier(0);  // pin: loads may NOT sink past here
    mlp_row(hh + 1, bufB, p, diff, b1, w2);
#pragma unroll
    for (int j = 0; j < 12; ++j)
      bufB[j] = w1r[((hh + 3) & (HIDN - 1)) * 12 + j];  // prefetch row hh+3
    __builtin_amdgcn_sched_barrier(0);  // pin
  }

  const float m = jax_mask_bit(key0, key1, g);

  float* nb = nxt + (size_t)b * CC * HWSZ + hw;
#pragma unroll
  for (int c = 0; c < CC; ++c) {
    nb[c * HWSZ] = fmaf(diff[c], m, p[c]);  // exact: m in {0,1}
  }
}

// ---------------------------------------------------------------------------
// Kernel B: 3x3 max-pool on alpha (ch 3), alive gate, write next state
// ---------------------------------------------------------------------------
__global__ __launch_bounds__(256) void ca_step_alive(
    const float* __restrict__ nw, float* __restrict__ out) {
  const int g = blockIdx.x * 256 + threadIdx.x;
  const int b = g >> 14;
  const int hw = g & (HWSZ - 1);
  const int h = hw >> 7;
  const int w = hw & (WW - 1);
  const bool hu = h > 0, hd = h < HH_ - 1, wl = w > 0, wr = w < WW - 1;

  const float* ab = nw + ((size_t)b * CC + 3) * HWSZ + hw;
  float pooled = ab[0];
  if (hu) {
    pooled = fmaxf(pooled, ab[-WW]);
    if (wl) pooled = fmaxf(pooled, ab[-WW - 1]);
    if (wr) pooled = fmaxf(pooled, ab[-WW + 1]);
  }
  if (hd) {
    pooled = fmaxf(pooled, ab[WW]);
    if (wl) pooled = fmaxf(pooled, ab[WW - 1]);
    if (wr) pooled = fmaxf(pooled, ab[WW + 1]);
  }
  if (wl) pooled = fmaxf(pooled, ab[-1]);
  if (wr) pooled = fmaxf(pooled, ab[1]);

  const float alive = (pooled > 0.1f) ? 1.0f : 0.0f;

  const float* nb = nw + (size_t)b * CC * HWSZ + hw;
  float* ob = out + (size_t)b * CC * HWSZ + hw;
#pragma unroll
  for (int c = 0; c < CC; ++c) ob[c * HWSZ] = nb[c * HWSZ] * alive;
}

// ---------------------------------------------------------------------------
extern "C" void kernel_launch(void* const* d_in, const int* in_sizes, int n_in,
                              void* d_out, int out_size, void* d_ws,
                              size_t ws_size, hipStream_t stream) {
  const float* x = (const float*)d_in[0];
  const float* w1 = (const float*)d_in[1];
  const float* b1 = (const float*)d_in[2];
  const float* w2 = (const float*)d_in[3];
  const float* b2 = (const float*)d_in[4];
  // d_in[5] = n_steps (16) — fixed at compile time

  float* out = (float*)d_out;
  float* nbuf = (float*)d_ws;  // NPIX*CC*4 = 8 MB scratch

  // step keys from split(key(42), 16), partitionable threefry
  uint32_t k0s[NSTEPS], k1s[NSTEPS];
  for (int s = 0; s < NSTEPS; ++s)
    threefry2x32(0u, 42u, 0u, (uint32_t)s, &k0s[s], &k1s[s]);

  dim3 grid(NPIX / 256), block(256);
  for (int s = 0; s < NSTEPS; ++s) {
    const float* src = (s == 0) ? x : out;
    ca_step_mlp<<<grid, block, 0, stream>>>(src, w1, b1, w2, b2, nbuf,
                                            k0s[s], k1s[s]);
    ca_step_alive<<<grid, block, 0, stream>>>(nbuf, out);
  }
}

// Round 9
// 959.311 us; speedup vs baseline: 1.7634x; 1.7441x over previous
//
#include <hip/hip_runtime.h>
#include <stdint.h>

// CA model constants (match reference)
#define BB 8
#define CC 16
#define HH_ 128
#define WW 128
#define HIDN 128
#define HWSZ (HH_ * WW)          // 16384
#define NPIX (BB * HWSZ)         // 131072
#define NSTEPS 16

// ---------------------------------------------------------------------------
// Threefry-2x32, 20 rounds — exact JAX implementation (partitionable mode).
// ---------------------------------------------------------------------------
__host__ __device__ inline void threefry2x32(uint32_t k0, uint32_t k1,
                                             uint32_t x0, uint32_t x1,
                                             uint32_t* o0, uint32_t* o1) {
  uint32_t ks[3] = {k0, k1, k0 ^ k1 ^ 0x1BD11BDAu};
  const uint32_t rots[2][4] = {{13u, 15u, 26u, 6u}, {17u, 29u, 16u, 24u}};
  x0 += ks[0];
  x1 += ks[1];
#pragma unroll
  for (int g = 0; g < 5; ++g) {
    const uint32_t* r = rots[g & 1];
#pragma unroll
    for (int i = 0; i < 4; ++i) {
      x0 += x1;
      x1 = (x1 << r[i]) | (x1 >> (32u - r[i]));
      x1 ^= x0;
    }
    x0 += ks[(g + 1) % 3];
    x1 += ks[(g + 2) % 3] + (uint32_t)(g + 1);
  }
  *o0 = x0;
  *o1 = x1;
}

__device__ __forceinline__ float jax_mask_bit(uint32_t key0, uint32_t key1, int g) {
  uint32_t t0, t1;
  threefry2x32(key0, key1, 0u, (uint32_t)g, &t0, &t1);
  uint32_t bits = t0 ^ t1;
  float u = __uint_as_float((bits >> 9) | 0x3f800000u) - 1.0f;
  return (u < 0.5f) ? 1.0f : 0.0f;
}

// ---------------------------------------------------------------------------
// Kernel A: sobel perception + MLP + mask -> writes "new" state to nxt
//
// R9 = R0 (best measured, 58us/mlp, 830us total) + per-iteration
// __syncthreads() to LOCKSTEP the block's 4 waves on the scalar weight
// stream. Path ledger after 8 rounds (all measured):
//   s_load w1 (R0): 58us — per-row lgkmcnt(0) drain; un-double-bufferable
//     (48-SGPR row at the SGPR ceiling).
//   LDS broadcast (R1): 80us — DS pipe 16 b128 x 8 waves x 12cy.
//   VMEM broadcast (R3/R7/R8): 104-130us — compiler collapses every form
//     of source-level double-buffer (naive, manual, sched_barrier-pinned).
//     VMEM path declared dead at HIP source level.
//   Occupancy 2x (R6): no effect — sL1 misses serialize per-CU.
// R6's serialization + 8 drifted waves re-streaming the same 24KB w1
// (> ~16KB sL1 -> 100% miss) is the remaining explanation of the drain.
// The barrier aligns the 4 waves at the same hh row: their 12 s_loads hit
// the same 3-4 cache lines -> 1 miss serves 4 waves (4x less scalar L2
// traffic); the two co-resident blocks run anti-phase (drain || FMA).
// Cost ~0; worst case this IS the R0 kernel.
// ---------------------------------------------------------------------------
__global__ __launch_bounds__(256, 2) void ca_step_mlp(
    const float* __restrict__ cur, const float* __restrict__ w1,
    const float* __restrict__ b1, const float* __restrict__ w2,
    const float* __restrict__ b2, float* __restrict__ nxt,
    uint32_t key0, uint32_t key1) {
  __shared__ float lw2t[HIDN * CC];  // 8192 B, [hh][o]

  // stage w2 transposed: coalesced global read, scattered LDS write (one-time)
  for (int i = threadIdx.x; i < HIDN * CC; i += 256) {
    int o = i >> 7;           // i / 128
    int hh = i & (HIDN - 1);  // i % 128
    lw2t[hh * CC + o] = w2[i];
  }
  __syncthreads();

  const int g = blockIdx.x * 256 + threadIdx.x;  // 0..NPIX-1
  const int b = g >> 14;
  const int hw = g & (HWSZ - 1);
  const int h = hw >> 7;
  const int w = hw & (WW - 1);

  const bool hu = h > 0, hd = h < HH_ - 1, wl = w > 0, wr = w < WW - 1;
  const int du = hu ? -WW : 0;
  const int dd = hd ? WW : 0;
  const int dl = wl ? -1 : 0;
  const int dr = wr ? 1 : 0;

  const float* xb = cur + (size_t)b * CC * HWSZ + hw;

  // perception: [ident(16) | sobel_x(16) | sobel_y(16)]
  float p[48];
#pragma unroll
  for (int c = 0; c < CC; ++c) {
    const float* xc = xb + c * HWSZ;
    float n00 = xc[du + dl]; if (!(hu && wl)) n00 = 0.f;
    float n01 = xc[du];      if (!hu)         n01 = 0.f;
    float n02 = xc[du + dr]; if (!(hu && wr)) n02 = 0.f;
    float n10 = xc[dl];      if (!wl)         n10 = 0.f;
    float n11 = xc[0];
    float n12 = xc[dr];      if (!wr)         n12 = 0.f;
    float n20 = xc[dd + dl]; if (!(hd && wl)) n20 = 0.f;
    float n21 = xc[dd];      if (!hd)         n21 = 0.f;
    float n22 = xc[dd + dr]; if (!(hd && wr)) n22 = 0.f;
    p[c] = n11;
    p[16 + c] = (n00 - n02 + 2.f * (n10 - n12) + n20 - n22) * 0.125f;
    p[32 + c] = (n00 + 2.f * n01 + n02 - n20 - 2.f * n21 - n22) * 0.125f;
  }

  float diff[CC];
#pragma unroll
  for (int o = 0; o < CC; ++o) diff[o] = b2[o];  // uniform -> s_load

#pragma unroll 1
  for (int hh = 0; hh < HIDN; ++hh) {
    // Lockstep the block's 4 waves: same hh -> same w1 cache lines -> one
    // sL1 miss serves 4 waves. (All outstanding loads are consumed before
    // this point, so the barrier's implied waitcnt drain is a no-op.)
    __syncthreads();
    // wave-uniform address -> compiler emits s_load_dwordx4 (scalar pipe)
    const float4* wrow = (const float4*)(w1 + hh * 48);
    float a0 = b1[hh], a1 = 0.f, a2 = 0.f, a3 = 0.f;
#pragma unroll
    for (int q = 0; q < 3; ++q) {
      float4 w0 = wrow[q * 4 + 0];
      float4 w1v = wrow[q * 4 + 1];
      float4 w2v = wrow[q * 4 + 2];
      float4 w3 = wrow[q * 4 + 3];
      const int base = q * 16;
      a0 = fmaf(w0.x, p[base + 0], a0);
      a0 = fmaf(w0.y, p[base + 1], a0);
      a0 = fmaf(w0.z, p[base + 2], a0);
      a0 = fmaf(w0.w, p[base + 3], a0);
      a1 = fmaf(w1v.x, p[base + 4], a1);
      a1 = fmaf(w1v.y, p[base + 5], a1);
      a1 = fmaf(w1v.z, p[base + 6], a1);
      a1 = fmaf(w1v.w, p[base + 7], a1);
      a2 = fmaf(w2v.x, p[base + 8], a2);
      a2 = fmaf(w2v.y, p[base + 9], a2);
      a2 = fmaf(w2v.z, p[base + 10], a2);
      a2 = fmaf(w2v.w, p[base + 11], a2);
      a3 = fmaf(w3.x, p[base + 12], a3);
      a3 = fmaf(w3.y, p[base + 13], a3);
      a3 = fmaf(w3.z, p[base + 14], a3);
      a3 = fmaf(w3.w, p[base + 15], a3);
    }
    float acc = (a0 + a1) + (a2 + a3);
    acc = fmaxf(acc, 0.f);
    const float4* w2row = (const float4*)(lw2t + hh * CC);  // broadcast b128
#pragma unroll
    for (int o4 = 0; o4 < 4; ++o4) {
      float4 wv = w2row[o4];
      diff[o4 * 4 + 0] = fmaf(wv.x, acc, diff[o4 * 4 + 0]);
      diff[o4 * 4 + 1] = fmaf(wv.y, acc, diff[o4 * 4 + 1]);
      diff[o4 * 4 + 2] = fmaf(wv.z, acc, diff[o4 * 4 + 2]);
      diff[o4 * 4 + 3] = fmaf(wv.w, acc, diff[o4 * 4 + 3]);
    }
  }

  const float m = jax_mask_bit(key0, key1, g);

  float* nb = nxt + (size_t)b * CC * HWSZ + hw;
#pragma unroll
  for (int c = 0; c < CC; ++c) {
    nb[c * HWSZ] = fmaf(diff[c], m, p[c]);  // exact: m in {0,1}
  }
}

// ---------------------------------------------------------------------------
// Kernel B: 3x3 max-pool on alpha (ch 3), alive gate, write next state
// ---------------------------------------------------------------------------
__global__ __launch_bounds__(256) void ca_step_alive(
    const float* __restrict__ nw, float* __restrict__ out) {
  const int g = blockIdx.x * 256 + threadIdx.x;
  const int b = g >> 14;
  const int hw = g & (HWSZ - 1);
  const int h = hw >> 7;
  const int w = hw & (WW - 1);
  const bool hu = h > 0, hd = h < HH_ - 1, wl = w > 0, wr = w < WW - 1;

  const float* ab = nw + ((size_t)b * CC + 3) * HWSZ + hw;
  float pooled = ab[0];
  if (hu) {
    pooled = fmaxf(pooled, ab[-WW]);
    if (wl) pooled = fmaxf(pooled, ab[-WW - 1]);
    if (wr) pooled = fmaxf(pooled, ab[-WW + 1]);
  }
  if (hd) {
    pooled = fmaxf(pooled, ab[WW]);
    if (wl) pooled = fmaxf(pooled, ab[WW - 1]);
    if (wr) pooled = fmaxf(pooled, ab[WW + 1]);
  }
  if (wl) pooled = fmaxf(pooled, ab[-1]);
  if (wr) pooled = fmaxf(pooled, ab[1]);

  const float alive = (pooled > 0.1f) ? 1.0f : 0.0f;

  const float* nb = nw + (size_t)b * CC * HWSZ + hw;
  float* ob = out + (size_t)b * CC * HWSZ + hw;
#pragma unroll
  for (int c = 0; c < CC; ++c) ob[c * HWSZ] = nb[c * HWSZ] * alive;
}

// ---------------------------------------------------------------------------
extern "C" void kernel_launch(void* const* d_in, const int* in_sizes, int n_in,
                              void* d_out, int out_size, void* d_ws,
                              size_t ws_size, hipStream_t stream) {
  const float* x = (const float*)d_in[0];
  const float* w1 = (const float*)d_in[1];
  const float* b1 = (const float*)d_in[2];
  const float* w2 = (const float*)d_in[3];
  const float* b2 = (const float*)d_in[4];
  // d_in[5] = n_steps (16) — fixed at compile time

  float* out = (float*)d_out;
  float* nbuf = (float*)d_ws;  // NPIX*CC*4 = 8 MB scratch

  // step keys from split(key(42), 16), partitionable threefry
  uint32_t k0s[NSTEPS], k1s[NSTEPS];
  for (int s = 0; s < NSTEPS; ++s)
    threefry2x32(0u, 42u, 0u, (uint32_t)s, &k0s[s], &k1s[s]);

  dim3 grid(NPIX / 256), block(256);
  for (int s = 0; s < NSTEPS; ++s) {
    const float* src = (s == 0) ? x : out;
    ca_step_mlp<<<grid, block, 0, stream>>>(src, w1, b1, w2, b2, nbuf,
                                            k0s[s], k1s[s]);
    ca_step_alive<<<grid, block, 0, stream>>>(nbuf, out);
  }
}